// Round 6
// baseline (36.497 us; speedup 1.0000x reference)
//
#include <hip/hip_runtime.h>

// SimpleRPMGLoss: out = mean(smooth_l1(pred[:,:3], tgt[:,:3]))
//               + 100 * mean(acos(clip((sum(R(pred_e)*R(tgt_e)) - 1)/2)))
// B = 2,097,152 rows x 6 f32 each input (~100 MB read). Memory-bound streaming reduction.
//
// Fused single-dispatch, last-block-done finisher:
//  - lb(256,4): 128-VGPR budget so all 12 hoisted dwordx4 results stay live.
//    (Round 4's 42us fused regression was VGPR=32 codegen serializing the loads,
//     NOT the atomics: FETCH_SIZE was unchanged, VALU time normal, MLP collapsed.)
//  - relaxed agent-scope atomics only (no ACQ_REL RMW: that emits buffer_wbl2 +
//    buffer_inv per block on gfx950 -> 114us in round 3).
//  - no memset: finisher triggers on (old mod NBLK)==NBLK-1. 2048 consecutive
//    fetch_add returns cover every residue mod 2048 exactly once (2048 | 2^32),
//    so exactly one block triggers per launch from ANY counter start value
//    (0xAA poison, or accumulated value across graph replays). Output does not
//    depend on which block triggers -> deterministic.

constexpr int   B_ROWS  = 2097152;
constexpr int   NBLK    = 2048;             // 8 blocks/CU on 256 CUs
constexpr int   TPB     = 256;
constexpr int   NTHREAD = NBLK * TPB;       // 524288 threads; 2 row-pairs each
constexpr float ANGLE_WEIGHT = 100.0f;
constexpr float EPS_F        = 1e-7f;

typedef float f32x4 __attribute__((ext_vector_type(4)));

__device__ inline float smooth_l1_term(float d) {
    float ad = fabsf(d);
    return ad < 1.0f ? 0.5f * d * d : ad - 0.5f;
}

__device__ inline void euler_xyz_mat(float a, float b, float c, float r[9]) {
    float sa, ca, sb, cb, sc, cc;
    __sincosf(a, &sa, &ca);
    __sincosf(b, &sb, &cb);
    __sincosf(c, &sc, &cc);
    r[0] = cb * cc;
    r[1] = cc * sa * sb - ca * sc;
    r[2] = sc * sa + ca * cc * sb;
    r[3] = cb * sc;
    r[4] = ca * cc + sa * sb * sc;
    r[5] = ca * sb * sc - cc * sa;
    r[6] = -sb;
    r[7] = cb * sa;
    r[8] = ca * cb;
}

__device__ inline void accum_row(float px, float py, float pz,
                                 float pa, float pb, float pc,
                                 float tx, float ty, float tz,
                                 float ta, float tb, float tc,
                                 float& trans_acc, float& rot_acc) {
    trans_acc += smooth_l1_term(px - tx) + smooth_l1_term(py - ty) + smooth_l1_term(pz - tz);
    float rp[9], rt[9];
    euler_xyz_mat(pa, pb, pc, rp);
    euler_xyz_mat(ta, tb, tc, rt);
    float tr = 0.0f;
#pragma unroll
    for (int i = 0; i < 9; ++i) tr = fmaf(rp[i], rt[i], tr);
    float cosang = fminf(fmaxf((tr - 1.0f) * 0.5f, -1.0f + EPS_F), 1.0f - EPS_F);
    rot_acc += acosf(cosang);
}

__global__ __launch_bounds__(TPB, 4) void rpmg_fused_kernel(const float* __restrict__ pred,
                                                            const float* __restrict__ tgt,
                                                            float2* __restrict__ partial,
                                                            unsigned int* __restrict__ counter,
                                                            float* __restrict__ out) {
    const int tid = blockIdx.x * TPB + threadIdx.x;
    const f32x4* pp1 = reinterpret_cast<const f32x4*>(pred) + (size_t)tid * 3;
    const f32x4* tp1 = reinterpret_cast<const f32x4*>(tgt)  + (size_t)tid * 3;
    const f32x4* pp2 = pp1 + (size_t)NTHREAD * 3;
    const f32x4* tp2 = tp1 + (size_t)NTHREAD * 3;

    // Issue ALL 12 loads up front (48 data VGPRs live; budget is 128).
    f32x4 a0 = pp1[0], a1 = pp1[1], a2 = pp1[2];
    f32x4 b0 = tp1[0], b1 = tp1[1], b2 = tp1[2];
    f32x4 c0 = pp2[0], c1 = pp2[1], c2 = pp2[2];
    f32x4 d0 = tp2[0], d1 = tp2[1], d2 = tp2[2];

    float trans_acc = 0.0f, rot_acc = 0.0f;
    accum_row(a0[0], a0[1], a0[2], a0[3], a1[0], a1[1],
              b0[0], b0[1], b0[2], b0[3], b1[0], b1[1], trans_acc, rot_acc);
    accum_row(a1[2], a1[3], a2[0], a2[1], a2[2], a2[3],
              b1[2], b1[3], b2[0], b2[1], b2[2], b2[3], trans_acc, rot_acc);
    accum_row(c0[0], c0[1], c0[2], c0[3], c1[0], c1[1],
              d0[0], d0[1], d0[2], d0[3], d1[0], d1[1], trans_acc, rot_acc);
    accum_row(c1[2], c1[3], c2[0], c2[1], c2[2], c2[3],
              d1[2], d1[3], d2[0], d2[1], d2[2], d2[3], trans_acc, rot_acc);

    // Block reduction.
#pragma unroll
    for (int off = 32; off > 0; off >>= 1) {
        trans_acc += __shfl_down(trans_acc, off, 64);
        rot_acc   += __shfl_down(rot_acc,   off, 64);
    }
    __shared__ float sa[TPB / 64], sb[TPB / 64];
    __shared__ int   s_last;
    const int wid  = threadIdx.x >> 6;
    const int lane = threadIdx.x & 63;
    if (lane == 0) { sa[wid] = trans_acc; sb[wid] = rot_acc; }
    __syncthreads();
    if (threadIdx.x == 0) {
        float ta = 0.0f, tb = 0.0f;
#pragma unroll
        for (int w = 0; w < TPB / 64; ++w) { ta += sa[w]; tb += sb[w]; }
        // Write-through to the coherence point (no L2 wb/inv), then hand-rolled
        // release: wait for store ack, then relaxed RMW on the counter.
        __hip_atomic_store(&partial[blockIdx.x].x, ta, __ATOMIC_RELAXED, __HIP_MEMORY_SCOPE_AGENT);
        __hip_atomic_store(&partial[blockIdx.x].y, tb, __ATOMIC_RELAXED, __HIP_MEMORY_SCOPE_AGENT);
        asm volatile("s_waitcnt vmcnt(0)" ::: "memory");
        unsigned int old = __hip_atomic_fetch_add(counter, 1u, __ATOMIC_RELAXED, __HIP_MEMORY_SCOPE_AGENT);
        s_last = ((old & (unsigned int)(NBLK - 1)) == (unsigned int)(NBLK - 1)) ? 1 : 0;
    }
    __syncthreads();

    if (s_last) {
        // Exactly one block per launch reaches here, after all partials are at
        // the coherence point. Fixed-order reduction -> deterministic output.
        float ta = 0.0f, tb = 0.0f;
        for (int i = threadIdx.x; i < NBLK; i += TPB) {
            ta += __hip_atomic_load(&partial[i].x, __ATOMIC_RELAXED, __HIP_MEMORY_SCOPE_AGENT);
            tb += __hip_atomic_load(&partial[i].y, __ATOMIC_RELAXED, __HIP_MEMORY_SCOPE_AGENT);
        }
#pragma unroll
        for (int off = 32; off > 0; off >>= 1) {
            ta += __shfl_down(ta, off, 64);
            tb += __shfl_down(tb, off, 64);
        }
        __syncthreads();   // sa/sb reuse
        if (lane == 0) { sa[wid] = ta; sb[wid] = tb; }
        __syncthreads();
        if (threadIdx.x == 0) {
            float st = 0.0f, sr = 0.0f;
#pragma unroll
            for (int w = 0; w < TPB / 64; ++w) { st += sa[w]; sr += sb[w]; }
            out[0] = st / (3.0f * (float)B_ROWS) + ANGLE_WEIGHT * (sr / (float)B_ROWS);
        }
    }
}

extern "C" void kernel_launch(void* const* d_in, const int* in_sizes, int n_in,
                              void* d_out, int out_size, void* d_ws, size_t ws_size,
                              hipStream_t stream) {
    const float* pred = (const float*)d_in[0];
    const float* tgt  = (const float*)d_in[1];
    float* out        = (float*)d_out;

    float2*       partial = (float2*)d_ws;                                   // 16 KB
    unsigned int* counter = (unsigned int*)((char*)d_ws + NBLK * sizeof(float2));

    rpmg_fused_kernel<<<NBLK, TPB, 0, stream>>>(pred, tgt, partial, counter, out);
}

// Round 7
// 24.373 us; speedup vs baseline: 1.4974x; 1.4974x over previous
//
#include <hip/hip_runtime.h>

// SimpleRPMGLoss: out = mean(smooth_l1(pred[:,:3], tgt[:,:3]))
//               + 100 * mean(acos(clip((sum(R(pred_e)*R(tgt_e)) - 1)/2)))
// B = 2,097,152 rows x 6 f32 each input (~100 MB read). Memory-latency-bound
// streaming reduction (replays are ~50% Infinity-Cache-warm).
//
// Two-kernel structure (proven: 24.3us, absmax 0.0; fused last-block-done
// variants REGRESSED: 2048 same-address agent RMWs serialize ~9ns each at the
// coherence point => ~19us tail at near-zero occupancy; ACQ_REL adds L2 wb/inv
// => 114us. Counter mod-tricks also race the finisher: absmax 0.0 -> 1.0).
//
// k1 MLP fix: the backend re-sinks source-hoisted loads (VGPR=32, ~3 loads in
// flight, 5.3 TB/s effective). An asm operand pin after the 12 dwordx4 loads
// forces all 12 to ISSUE before any consumption: one vmcnt stall with 768 B
// per wave in flight (~15 KB/CU outstanding).

constexpr int   B_ROWS  = 2097152;
constexpr int   NBLK    = 2048;             // 8 blocks/CU on 256 CUs
constexpr int   TPB     = 256;
constexpr int   NTHREAD = NBLK * TPB;       // 524288 threads; 2 row-pairs each
constexpr float ANGLE_WEIGHT = 100.0f;
constexpr float EPS_F        = 1e-7f;

typedef float f32x4 __attribute__((ext_vector_type(4)));

__device__ inline float smooth_l1_term(float d) {
    float ad = fabsf(d);
    return ad < 1.0f ? 0.5f * d * d : ad - 0.5f;
}

__device__ inline void euler_xyz_mat(float a, float b, float c, float r[9]) {
    float sa, ca, sb, cb, sc, cc;
    __sincosf(a, &sa, &ca);
    __sincosf(b, &sb, &cb);
    __sincosf(c, &sc, &cc);
    r[0] = cb * cc;
    r[1] = cc * sa * sb - ca * sc;
    r[2] = sc * sa + ca * cc * sb;
    r[3] = cb * sc;
    r[4] = ca * cc + sa * sb * sc;
    r[5] = ca * sb * sc - cc * sa;
    r[6] = -sb;
    r[7] = cb * sa;
    r[8] = ca * cb;
}

__device__ inline void accum_row(float px, float py, float pz,
                                 float pa, float pb, float pc,
                                 float tx, float ty, float tz,
                                 float ta, float tb, float tc,
                                 float& trans_acc, float& rot_acc) {
    trans_acc += smooth_l1_term(px - tx) + smooth_l1_term(py - ty) + smooth_l1_term(pz - tz);
    float rp[9], rt[9];
    euler_xyz_mat(pa, pb, pc, rp);
    euler_xyz_mat(ta, tb, tc, rt);
    float tr = 0.0f;
#pragma unroll
    for (int i = 0; i < 9; ++i) tr = fmaf(rp[i], rt[i], tr);
    float cosang = fminf(fmaxf((tr - 1.0f) * 0.5f, -1.0f + EPS_F), 1.0f - EPS_F);
    rot_acc += acosf(cosang);
}

// lb(256,4): VGPR cap 128 — room for 48 live load-result VGPRs without spill.
__global__ __launch_bounds__(TPB, 4) void rpmg_partial_kernel(const float* __restrict__ pred,
                                                              const float* __restrict__ tgt,
                                                              float2* __restrict__ partial) {
    const int tid = blockIdx.x * TPB + threadIdx.x;
    const f32x4* pp1 = reinterpret_cast<const f32x4*>(pred) + (size_t)tid * 3;
    const f32x4* tp1 = reinterpret_cast<const f32x4*>(tgt)  + (size_t)tid * 3;
    const f32x4* pp2 = pp1 + (size_t)NTHREAD * 3;
    const f32x4* tp2 = tp1 + (size_t)NTHREAD * 3;

    // Issue ALL 12 dwordx4 loads...
    f32x4 a0 = pp1[0], a1 = pp1[1], a2 = pp1[2];
    f32x4 b0 = tp1[0], b1 = tp1[1], b2 = tp1[2];
    f32x4 c0 = pp2[0], c1 = pp2[1], c2 = pp2[2];
    f32x4 d0 = tp2[0], d1 = tp2[1], d2 = tp2[2];
    // ...and PIN them: forces the backend to issue all 12 before any use
    // (one vmcnt stall, 12 loads in flight) instead of sinking to ~3-in-flight.
    asm volatile("" :: "v"(a0), "v"(a1), "v"(a2), "v"(b0), "v"(b1), "v"(b2),
                       "v"(c0), "v"(c1), "v"(c2), "v"(d0), "v"(d1), "v"(d2));

    float trans_acc = 0.0f, rot_acc = 0.0f;
    accum_row(a0[0], a0[1], a0[2], a0[3], a1[0], a1[1],
              b0[0], b0[1], b0[2], b0[3], b1[0], b1[1], trans_acc, rot_acc);
    accum_row(a1[2], a1[3], a2[0], a2[1], a2[2], a2[3],
              b1[2], b1[3], b2[0], b2[1], b2[2], b2[3], trans_acc, rot_acc);
    accum_row(c0[0], c0[1], c0[2], c0[3], c1[0], c1[1],
              d0[0], d0[1], d0[2], d0[3], d1[0], d1[1], trans_acc, rot_acc);
    accum_row(c1[2], c1[3], c2[0], c2[1], c2[2], c2[3],
              d1[2], d1[3], d2[0], d2[1], d2[2], d2[3], trans_acc, rot_acc);

    // Block reduction -> one float2 per block (plain store; dispatch-boundary
    // release/acquire makes it visible to kernel 2).
#pragma unroll
    for (int off = 32; off > 0; off >>= 1) {
        trans_acc += __shfl_down(trans_acc, off, 64);
        rot_acc   += __shfl_down(rot_acc,   off, 64);
    }
    __shared__ float sa[TPB / 64], sb[TPB / 64];
    const int wid  = threadIdx.x >> 6;
    const int lane = threadIdx.x & 63;
    if (lane == 0) { sa[wid] = trans_acc; sb[wid] = rot_acc; }
    __syncthreads();
    if (threadIdx.x == 0) {
        float ta = 0.0f, tb = 0.0f;
#pragma unroll
        for (int w = 0; w < TPB / 64; ++w) { ta += sa[w]; tb += sb[w]; }
        partial[blockIdx.x] = make_float2(ta, tb);
    }
}

__global__ __launch_bounds__(TPB) void rpmg_final_kernel(const float2* __restrict__ partial,
                                                         float* __restrict__ out) {
    float ta = 0.0f, tb = 0.0f;
    for (int i = threadIdx.x; i < NBLK; i += TPB) {
        float2 v = partial[i];
        ta += v.x;
        tb += v.y;
    }
#pragma unroll
    for (int off = 32; off > 0; off >>= 1) {
        ta += __shfl_down(ta, off, 64);
        tb += __shfl_down(tb, off, 64);
    }
    __shared__ float sa[TPB / 64], sb[TPB / 64];
    const int wid  = threadIdx.x >> 6;
    const int lane = threadIdx.x & 63;
    if (lane == 0) { sa[wid] = ta; sb[wid] = tb; }
    __syncthreads();
    if (threadIdx.x == 0) {
        float st = 0.0f, sr = 0.0f;
#pragma unroll
        for (int w = 0; w < TPB / 64; ++w) { st += sa[w]; sr += sb[w]; }
        out[0] = st / (3.0f * (float)B_ROWS) + ANGLE_WEIGHT * (sr / (float)B_ROWS);
    }
}

extern "C" void kernel_launch(void* const* d_in, const int* in_sizes, int n_in,
                              void* d_out, int out_size, void* d_ws, size_t ws_size,
                              hipStream_t stream) {
    const float* pred = (const float*)d_in[0];
    const float* tgt  = (const float*)d_in[1];
    float* out        = (float*)d_out;
    float2* partial   = (float2*)d_ws;      // 16 KB scratch

    rpmg_partial_kernel<<<NBLK, TPB, 0, stream>>>(pred, tgt, partial);
    rpmg_final_kernel<<<1, TPB, 0, stream>>>(partial, out);
}